// Round 3
// baseline (3608.886 us; speedup 1.0000x reference)
//
#include <hip/hip_runtime.h>

#define SEQ  128
#define B_   512
#define HID_ 512
#define NKT  24

typedef _Float16 f16;
typedef _Float16 f16x8 __attribute__((ext_vector_type(8)));
typedef float    f32x4 __attribute__((ext_vector_type(4)));

// ws layout (bytes), total 78,643,204
#define OFF_BT   0u          // [4096][1024] f16 (r<512: Wih, r>=512: Whh)
#define OFF_X16  8388608u    // [128][512][512] f16
#define OFF_MH   75497472u   // [2][262144] f16
#define OFF_ML   76546048u   // [2][262144] f16
#define OFF_C    77594624u   // [512][512] f32 (tier-3 only)
#define OFF_BAR  78643200u   // u32 arrival counter

#define SLOT  24576          // 8KB A + 16KB B per pipeline slot
#define NSLOT 5              // 120KB LDS, 5-deep pipeline (issue distance 4)

__device__ __forceinline__ void gll16(const void* g, void* l) {
  __builtin_amdgcn_global_load_lds(
      (const __attribute__((address_space(1))) unsigned int*)g,
      (__attribute__((address_space(3))) unsigned int*)l, 16, 0, 0);
}

__device__ __forceinline__ float sigm_f(float x) {
  return __fdividef(1.f, 1.f + __expf(-x));
}
__device__ __forceinline__ float tanh_f(float x) {
  x = fminf(fmaxf(x, -15.f), 15.f);
  float u = __expf(2.f * x);
  return __fdividef(u - 1.f, u + 1.f);
}

#define VW(n) asm volatile("s_waitcnt vmcnt(" #n ")" ::: "memory")

// ---- one-time prep --------------------------------------------------------
__global__ void build_bt(const float* __restrict__ wih,
                         const float* __restrict__ whh,
                         f16* __restrict__ bt) {
  int n  = blockIdx.x;                 // 0..4095 : n = ht*128 + k*16 + hl
  int hl = n & 15, k = (n >> 4) & 7, ht = n >> 7;
  int h  = ht * 16 + hl;
  const float* pih = wih + (size_t)k * 512 * 512 + h;
  const float* phh = whh + (size_t)k * 512 * 512 + h;
  f16* dst = bt + (size_t)n * 1024;
  for (int r = threadIdx.x; r < 512; r += 256) {
    dst[r]       = (f16)pih[(size_t)r * 512];
    dst[512 + r] = (f16)phh[(size_t)r * 512];
  }
}

__global__ void cvt_x(const float4* __restrict__ x, f16* __restrict__ y, int nvec) {
  typedef _Float16 f16x4v __attribute__((ext_vector_type(4)));
  int i = blockIdx.x * blockDim.x + threadIdx.x;
  int stride = gridDim.x * blockDim.x;
  f16x4v* yo = (f16x4v*)y;
  for (; i < nvec; i += stride) {
    float4 v = x[i];
    f16x4v o = { (f16)v.x, (f16)v.y, (f16)v.z, (f16)v.w };
    yo[i] = o;
  }
}

__global__ void init_state(f16* __restrict__ mh, f16* __restrict__ ml,
                           float* __restrict__ c, unsigned int* __restrict__ bar) {
  int i = blockIdx.x * blockDim.x + threadIdx.x;   // 1024x256 = 262144
  mh[i] = (f16)1.f;
  ml[i] = (f16)0.f;
  c[i]  = 1.f;
  if (i == 0) *bar = 0u;
}

// ---- tier 1/2: persistent fused RNN ---------------------------------------
// grid = 256 blocks (nt = bid&31, mt = bid>>5), 128 threads (2 waves).
// Block tile 64(M)x128(N); wave tile 32x128 (acc[2][8] f32x4).
// Phases/step (24): p=0..7 x@Wih[p*64..]; p=8+2j mh@Whh[j*64..]; p=9+2j ml
// reusing B fragments cached in regs at p=8+2j.
// 5-slot LDS pipeline, issue distance 4, counted vmcnt (never 0 in loop).
__global__ __launch_bounds__(128, 1)
void nas_persist(const f16* __restrict__ X, const f16* __restrict__ BT,
                 f16* __restrict__ MHb, f16* __restrict__ MLb,
                 unsigned int* __restrict__ bar, float* __restrict__ out) {
  __shared__ char lds[NSLOT * SLOT];
  const int tid  = threadIdx.x;
  const int lane = tid & 63;
  const int wid  = tid >> 6;
  const int nt   = blockIdx.x & 31;
  const int mt   = blockIdx.x >> 5;

  // stage phase pi of step ti into slot sl. Loads/thread: 12 if B staged else 4.
  auto stage = [&](int ti, int pi, int sl) {
    const f16* asrc; int acol, bcol; bool hasb;
    if (pi < 8) { asrc = X + (size_t)ti * 262144; acol = pi << 6; bcol = pi << 6; hasb = true; }
    else {
      int j = (pi - 8) >> 1;
      asrc = ((pi & 1) ? MLb : MHb) + (size_t)(ti & 1) * 262144;
      acol = j << 6; bcol = 512 + (j << 6); hasb = !(pi & 1);
    }
    char* As = lds + sl * SLOT;
    char* Bs = As + 8192;
#pragma unroll
    for (int pp = 0; pp < 4; ++pp) {            // A tile 64x64 f16 = 512 chunks
      int u = pp * 128 + tid; int r = u >> 3; int c = (u & 7) ^ (r & 7);
      gll16(asrc + (((size_t)(mt * 64 + r)) << 9) + acol + c * 8,
            As + (pp * 128 + wid * 64) * 16);
    }
    if (hasb) {
#pragma unroll
      for (int pp = 0; pp < 8; ++pp) {          // B tile 128x64 f16 = 1024 chunks
        int u = pp * 128 + tid; int r = u >> 3; int c = (u & 7) ^ (r & 7);
        gll16(BT + (size_t)(nt * 128 + r) * 1024 + bcol + c * 8,
              Bs + (pp * 128 + wid * 64) * 16);
      }
    }
  };

  f32x4 acc[2][8];
  f16x8 bfr[2][8];
  float creg[2][4];
#pragma unroll
  for (int mi = 0; mi < 2; ++mi)
#pragma unroll
    for (int q = 0; q < 4; ++q) creg[mi][q] = 1.f;

  for (int pp = 0; pp < 4; ++pp) stage(0, pp, pp);   // prologue

  int s0 = 0;                                   // (24*t) % 5
  for (int t = 0; t < SEQ; ++t) {
#pragma unroll
    for (int mi = 0; mi < 2; ++mi)
#pragma unroll
      for (int ni = 0; ni < 8; ++ni) acc[mi][ni] = (f32x4){0.f, 0.f, 0.f, 0.f};

#pragma unroll
    for (int p = 0; p < 24; ++p) {
      // counted waits: outstanding = loads of stages (p+1..p+3); 12 per hasb
      // stage, 4 per odd p>=9 stage; epilogue stores only add conservatism.
      if (p <= 5)       VW(36);
      else if (p <= 7)  VW(28);
      else if (p == 22) VW(28);
      else if (p == 23) VW(36);
      else if (p & 1)   VW(28);
      else              VW(20);
      __builtin_amdgcn_s_barrier();
      asm volatile("" ::: "memory");

      if (p == 4 && t > 0) {
        // all blocks' step t-1 epilogues must be visible before mh/ml staging
        if (tid == 0) {
          while (__hip_atomic_load(bar, __ATOMIC_RELAXED, __HIP_MEMORY_SCOPE_AGENT)
                 < (unsigned)(256 * t))
            __builtin_amdgcn_s_sleep(2);
          __builtin_amdgcn_fence(__ATOMIC_ACQUIRE, "agent");   // inv caches
        }
        __builtin_amdgcn_s_barrier();
      }

      { // issue phase p+4 (phases 0..3 of t+1 are x-only — safe pre-sync)
        int ti, pi;
        if (p < 20) { ti = t; pi = p + 4; }
        else        { ti = (t + 1 < SEQ) ? t + 1 : t; pi = p - 20; }
        stage(ti, pi, (s0 + p + 4) % NSLOT);
      }

      { // compute phase p from slot (s0+p)%5
        const char* As = lds + ((s0 + p) % NSLOT) * SLOT;
        const char* Bs = As + 8192;
        const bool hasb = (p < 8) || !(p & 1);
#pragma unroll
        for (int kk = 0; kk < 2; ++kk) {
          const int cb = (kk * 32 + ((lane >> 4) << 3)) * 2;
          f16x8 a[2];
#pragma unroll
          for (int mi = 0; mi < 2; ++mi) {
            int ra = wid * 32 + mi * 16 + (lane & 15);
            a[mi] = *(const f16x8*)(As + ra * 128 + (cb ^ ((ra & 7) << 4)));
          }
          if (hasb) {
#pragma unroll
            for (int ni = 0; ni < 8; ++ni) {
              int rb = ni * 16 + (lane & 15);
              bfr[kk][ni] = *(const f16x8*)(Bs + rb * 128 + (cb ^ ((rb & 7) << 4)));
            }
          }
#pragma unroll
          for (int mi = 0; mi < 2; ++mi)
#pragma unroll
            for (int ni = 0; ni < 8; ++ni)
              acc[mi][ni] = __builtin_amdgcn_mfma_f32_16x16x32_f16(
                  a[mi], bfr[kk][ni], acc[mi][ni], 0, 0, 0);
        }
      }
    }

    // epilogue: lane holds all 8 gates of (b,h); c lives in registers
    {
      const int h = nt * 16 + (lane & 15);
      f16* mho = MHb + (size_t)((t & 1) ^ 1) * 262144;
      f16* mlo = MLb + (size_t)((t & 1) ^ 1) * 262144;
#pragma unroll
      for (int mi = 0; mi < 2; ++mi) {
#pragma unroll
        for (int q = 0; q < 4; ++q) {
          int b = mt * 64 + wid * 32 + mi * 16 + ((lane >> 4) << 2) + q;
          size_t idx = ((size_t)b << 9) + h;
          float l10 = sigm_f(acc[mi][0][q]);
          float l11 = fmaxf(acc[mi][1][q], 0.f);
          float l12 = sigm_f(acc[mi][2][q]);
          float l13 = fmaxf(acc[mi][3][q], 0.f);
          float l14 = tanh_f(acc[mi][4][q]);
          float l15 = sigm_f(acc[mi][5][q]);
          float l16 = tanh_f(acc[mi][6][q]);
          float l17 = sigm_f(acc[mi][7][q]);
          float l20 = tanh_f(l10 * l11);
          float l21 = tanh_f(l12 + l13);
          float l22 = tanh_f(l14 * l15);
          float l23 = sigm_f(l16 + l17);
          float cn  = tanh_f(l20 + creg[mi][q]) * l21;
          float l31 = tanh_f(l22 + l23);
          float mn  = tanh_f(cn * l31);
          creg[mi][q] = cn;
          f16 mhv = (f16)mn;
          mho[idx] = mhv;
          mlo[idx] = (f16)(mn - (float)mhv);
          if (t == SEQ - 1) out[idx] = mn;
        }
      }
    }

    if (t < SEQ - 1) {
      __builtin_amdgcn_fence(__ATOMIC_RELEASE, "agent");  // drain + wb stores
      __builtin_amdgcn_s_barrier();
      if (tid == 0)
        __hip_atomic_fetch_add(bar, 1u, __ATOMIC_RELAXED, __HIP_MEMORY_SCOPE_AGENT);
    }

    s0 += 4; if (s0 >= NSLOT) s0 -= NSLOT;                // (24*(t+1)) % 5
  }
  asm volatile("s_waitcnt vmcnt(0)" ::: "memory");
}

// ---- tier 3: proven per-step kernel (round-1, adapted to 1024-wide BT) -----
__global__ __launch_bounds__(256)
void nas_step(const f16* __restrict__ xt, const f16* __restrict__ bt,
              const f16* __restrict__ mh_in, const f16* __restrict__ ml_in,
              f16* __restrict__ mh_out, f16* __restrict__ ml_out,
              float* __restrict__ cst, float* __restrict__ out, int last) {
  __shared__ char lds[49152];
  char* Abase = lds;
  char* Bbase = lds + 16384;
  const int tid  = threadIdx.x;
  const int lane = tid & 63;
  const int wid  = tid >> 6;
  const int nt   = blockIdx.x;
  const int mt   = blockIdx.y;
  const f16* asrc[3] = { xt, mh_in, ml_in };

  auto stageA = [&](int buf, int kt) {
    const f16* src = asrc[kt >> 3];
    int kofs = (kt & 7) * 64;
#pragma unroll
    for (int p = 0; p < 2; ++p) {
      int u = p * 256 + tid; int r = u >> 3; int c16 = (u & 7) ^ (r & 7);
      gll16(src + ((size_t)(mt * 64 + r) << 9) + kofs + c16 * 8,
            Abase + buf * 8192 + (p * 256 + wid * 64) * 16);
    }
  };
  auto stageB = [&](int buf, int kt) {
    int kg = (kt < 8) ? (kt << 6) : (512 + ((kt & 7) << 6));
#pragma unroll
    for (int p = 0; p < 4; ++p) {
      int u = p * 256 + tid; int r = u >> 3; int c16 = (u & 7) ^ (r & 7);
      gll16(bt + (size_t)(nt * 128 + r) * 1024 + kg + c16 * 8,
            Bbase + buf * 16384 + (p * 256 + wid * 64) * 16);
    }
  };

  f32x4 acc[8];
#pragma unroll
  for (int i = 0; i < 8; ++i) acc[i] = (f32x4){0.f, 0.f, 0.f, 0.f};

  stageA(0, 0); stageB(0, 0);
  __syncthreads();
  for (int kt = 0; kt < NKT; ++kt) {
    int cur = kt & 1;
    if (kt + 1 < NKT) { stageA(cur ^ 1, kt + 1); stageB(cur ^ 1, kt + 1); }
    const char* At = Abase + cur * 8192;
    const char* Bt = Bbase + cur * 16384;
#pragma unroll
    for (int kk = 0; kk < 2; ++kk) {
      int cb = (kk * 32 + ((lane >> 4) << 3)) * 2;
      int ra = wid * 16 + (lane & 15);
      f16x8 a = *(const f16x8*)(At + ra * 128 + (cb ^ ((ra & 7) << 4)));
#pragma unroll
      for (int ni = 0; ni < 8; ++ni) {
        int rb = ni * 16 + (lane & 15);
        f16x8 b = *(const f16x8*)(Bt + rb * 128 + (cb ^ ((rb & 7) << 4)));
        acc[ni] = __builtin_amdgcn_mfma_f32_16x16x32_f16(a, b, acc[ni], 0, 0, 0);
      }
    }
    __syncthreads();
  }

  const int h = nt * 16 + (lane & 15);
  const int rb4 = (lane >> 4) << 2;
#pragma unroll
  for (int q = 0; q < 4; ++q) {
    int b = mt * 64 + wid * 16 + rb4 + q;
    size_t idx = ((size_t)b << 9) + h;
    float l10 = sigm_f(acc[0][q]);
    float l11 = fmaxf(acc[1][q], 0.f);
    float l12 = sigm_f(acc[2][q]);
    float l13 = fmaxf(acc[3][q], 0.f);
    float l14 = tanh_f(acc[4][q]);
    float l15 = sigm_f(acc[5][q]);
    float l16 = tanh_f(acc[6][q]);
    float l17 = sigm_f(acc[7][q]);
    float l20 = tanh_f(l10 * l11);
    float l21 = tanh_f(l12 + l13);
    float l22 = tanh_f(l14 * l15);
    float l23 = sigm_f(l16 + l17);
    float cn  = tanh_f(l20 + cst[idx]) * l21;
    float l31 = tanh_f(l22 + l23);
    float mn  = tanh_f(cn * l31);
    cst[idx] = cn;
    f16 mhv = (f16)mn;
    mh_out[idx] = mhv;
    ml_out[idx] = (f16)(mn - (float)mhv);
    if (last) out[idx] = mn;
  }
}

// ---- host -----------------------------------------------------------------
extern "C" void kernel_launch(void* const* d_in, const int* in_sizes, int n_in,
                              void* d_out, int out_size, void* d_ws, size_t ws_size,
                              hipStream_t stream) {
  const float* inputs = (const float*)d_in[0];
  const float* wih    = (const float*)d_in[1];
  const float* whh    = (const float*)d_in[2];
  float* out = (float*)d_out;
  char* ws   = (char*)d_ws;

  f16*          BTp = (f16*)(ws + OFF_BT);
  f16*          Xp  = (f16*)(ws + OFF_X16);
  f16*          MHp = (f16*)(ws + OFF_MH);
  f16*          MLp = (f16*)(ws + OFF_ML);
  float*        Cp  = (float*)(ws + OFF_C);
  unsigned int* bp  = (unsigned int*)(ws + OFF_BAR);

  build_bt<<<4096, 256, 0, stream>>>(wih, whh, BTp);
  cvt_x<<<2048, 256, 0, stream>>>((const float4*)inputs, Xp, SEQ * B_ * 512 / 4);
  init_state<<<1024, 256, 0, stream>>>(MHp, MLp, Cp, bp);

  void* args[] = { (void*)&Xp, (void*)&BTp, (void*)&MHp, (void*)&MLp,
                   (void*)&bp, (void*)&out };
  hipError_t ce = hipLaunchCooperativeKernel((const void*)nas_persist, dim3(256),
                                             dim3(128), args, 0, stream);
  if (ce != hipSuccess) {
    (void)hipGetLastError();                    // clear sticky error
    nas_persist<<<dim3(256), dim3(128), 0, stream>>>(Xp, BTp, MHp, MLp, bp, out);
    if (hipGetLastError() != hipSuccess) {
      for (int t = 0; t < SEQ; ++t) {           // tier 3: proven per-step path
        int cur = t & 1;
        nas_step<<<dim3(32, 8), 256, 0, stream>>>(
            Xp + (size_t)t * B_ * 512, BTp,
            MHp + (size_t)cur * 262144, MLp + (size_t)cur * 262144,
            MHp + (size_t)(cur ^ 1) * 262144, MLp + (size_t)(cur ^ 1) * 262144,
            Cp, out, (t == SEQ - 1) ? 1 : 0);
      }
    }
  }
}